// Round 12
// baseline (439.593 us; speedup 1.0000x reference)
//
#include <hip/hip_runtime.h>
#include <hip/hip_bf16.h>

#define NN 50000
#define NE 500000
#define HID 128
#define LAYERS 3
#define RELS 8
#define BASES 30
#define GRAPHS 16
#define CLASSES 8
#define EPSV 1e-5f
#define KBIG 1152                 // 9 panels x 128
#define NSEG (NN * RELS)          // 400000 (dst,rel) segments
#define SCAN_CHUNK 1024
#define SCAN_NBLK2 ((NSEG + SCAN_CHUNK - 1) / SCAN_CHUNK)   // 391
#define PCHUNK 128
#define NSTRIPE ((NN + 127) / 128)                           // 391

typedef __attribute__((ext_vector_type(4))) float f32x4;    // MFMA accumulator

__device__ __forceinline__ float bf2f(unsigned short u) {
    union { unsigned int i; float f; } x; x.i = ((unsigned int)u) << 16; return x.f;
}
__device__ __forceinline__ unsigned short f2bf(float f) {
    __hip_bfloat16 b = __float2bfloat16(f);
    return *(unsigned short*)&b;
}
__device__ __forceinline__ unsigned char f2fp8(float v) {
    return (unsigned char)(__builtin_amdgcn_cvt_pk_fp8_f32(v, v, 0, false) & 0xFF);
}
// storage permutation: feature f lives at in-row position perm(f).
__device__ __forceinline__ int permf(int f) {
    return (f & 64) | ((f & 15) << 2) | ((f >> 4) & 3);
}
__device__ __forceinline__ int ipermf(int q) {
    return (q & 64) | ((q & 3) << 4) | ((q >> 2) & 15);
}
// async global->LDS, 16B per lane; LDS dest = wave-uniform base + lane*16
__device__ __forceinline__ void gload16(const void* g, void* l) {
    __builtin_amdgcn_global_load_lds(
        (const __attribute__((address_space(1))) unsigned int*)g,
        (__attribute__((address_space(3))) unsigned int*)l, 16, 0, 0);
}

// ---------------- wT8: [L][128 out][1152 k] fp8; k position = p*128 + permf(in_feat)
__global__ __launch_bounds__(256) void build_wcat(const float* __restrict__ basis,
                                                  const float* __restrict__ comp,
                                                  const float* __restrict__ root,
                                                  unsigned char* __restrict__ wt8) {
    int bid = blockIdx.x;
    int l = bid >> 6;               // 0..2
    int k0 = (bid & 63) << 1;       // 0,2,..,126
    __shared__ float cl[RELS * BASES];   // 240
    int tid = threadIdx.x;
    if (tid < RELS * BASES) cl[tid] = comp[l * RELS * BASES + tid];
    __syncthreads();
    int j = tid & 127;              // output col
    int k = k0 + (tid >> 7);        // input feat
    int pk = permf(k);
    const float* bp = basis + ((size_t)l * BASES * HID + k) * HID + j;
    float acc[RELS];
#pragma unroll
    for (int r = 0; r < RELS; ++r) acc[r] = 0.f;
    for (int b = 0; b < BASES; ++b) {
        float v = bp[(size_t)b * HID * HID];
#pragma unroll
        for (int r = 0; r < RELS; ++r) acc[r] += cl[r * BASES + b] * v;
    }
    unsigned char* wl = wt8 + (size_t)l * HID * KBIG;
#pragma unroll
    for (int r = 0; r < RELS; ++r)
        wl[(size_t)j * KBIG + (1 + r) * HID + pk] = f2fp8(acc[r]);
    wl[(size_t)j * KBIG + pk] = f2fp8(root[((size_t)l * HID + k) * HID + j]);
}

// ---------------- BN1 (eval mode) -> bf16, permuted feature storage
__global__ void bn1_kernel(const float* __restrict__ x, const float* __restrict__ gamma,
                           const float* __restrict__ beta, const float* __restrict__ mean,
                           const float* __restrict__ var, unsigned short* __restrict__ habf) {
    int idx = blockIdx.x * blockDim.x + threadIdx.x;
    if (idx >= NN * HID) return;
    int q = idx & (HID - 1);
    int n = idx >> 7;
    int f = ipermf(q);
    habf[idx] = f2bf((x[(n << 7) + f] - mean[f]) * rsqrtf(var[f] + EPSV) * gamma[f] + beta[f]);
}

// ---------------- degree count per (dst, rel) segment (int atomics)
__global__ void deg_kernel(const int* __restrict__ ei, const int* __restrict__ ea,
                           int* __restrict__ cnt) {
    int e = blockIdx.x * blockDim.x + threadIdx.x;
    if (e >= NE) return;
    atomicAdd(&cnt[ei[NE + e] * RELS + ea[e]], 1);
}

// ---------------- partial scan over 400K segments
__global__ __launch_bounds__(256) void scan_partial(const int* __restrict__ cnt,
                                                    int* __restrict__ rowptr,
                                                    int* __restrict__ bsum) {
    __shared__ int ssc[256];
    int t = threadIdx.x;
    int base = blockIdx.x * SCAN_CHUNK + t * 4;
    int v[4];
#pragma unroll
    for (int j = 0; j < 4; ++j) {
        int seg = base + j;
        v[j] = (seg < NSEG) ? cnt[seg] : 0;
    }
    int tsum = v[0] + v[1] + v[2] + v[3];
    ssc[t] = tsum;
    __syncthreads();
    for (int ofs = 1; ofs < 256; ofs <<= 1) {
        int add = (t >= ofs) ? ssc[t - ofs] : 0;
        __syncthreads();
        ssc[t] += add;
        __syncthreads();
    }
    int excl = ssc[t] - tsum;
    int e = 0;
#pragma unroll
    for (int j = 0; j < 4; ++j) {
        if (base + j < NSEG) rowptr[base + j] = excl + e;
        e += v[j];
    }
    if (t == 255) bsum[blockIdx.x] = ssc[255];
}

// parallel exclusive scan of the 391 block sums (one 512-thread block)
__global__ __launch_bounds__(512) void scan_bsum(int* __restrict__ bsum) {
    __shared__ int s[512];
    int t = threadIdx.x;
    int v = (t < SCAN_NBLK2) ? bsum[t] : 0;
    s[t] = v;
    __syncthreads();
    for (int o = 1; o < 512; o <<= 1) {
        int a = (t >= o) ? s[t - o] : 0;
        __syncthreads();
        s[t] += a;
        __syncthreads();
    }
    if (t < SCAN_NBLK2) bsum[t] = s[t] - v;
}

__global__ __launch_bounds__(256) void scan_add(int* __restrict__ rowptr,
                                                const int* __restrict__ bsum) {
    int i = blockIdx.x * blockDim.x + threadIdx.x;
    if (i < NSEG) rowptr[i] += bsum[i >> 10];
    if (i == 0) rowptr[NSEG] = NE;
}

// ---------------- fill CSR keyed by (dst,rel): epk2[slot] = src
__global__ void fill_kernel(const int* __restrict__ ei, const int* __restrict__ ea,
                            const int* __restrict__ rowptr,
                            int* __restrict__ fillcnt, int* __restrict__ epk) {
    int e = blockIdx.x * blockDim.x + threadIdx.x;
    if (e >= NE) return;
    int seg = ei[NE + e] * RELS + ea[e];
    int pos = atomicAdd(&fillcnt[seg], 1);
    epk[rowptr[seg] + pos] = ei[e];
}

// ---------------- aggregate-first: one wave per dst; slot 0 = fp8(x[dst]),
// slots 1+r = fp8(mean_{src in N_r} x[src]). Gathers hit L2-resident hin (12.8 MB).
// lane covers feature positions 2*lane, 2*lane+1 (storage space); wave writes 128B/slot.
__global__ __launch_bounds__(256) void agg_kernel(const unsigned short* __restrict__ hin,
                                                  const int* __restrict__ rp2,
                                                  const int* __restrict__ epk2,
                                                  unsigned char* __restrict__ aggbuf) {
    int lane = threadIdx.x & 63;
    int dst = (blockIdx.x << 2) + (threadIdx.x >> 6);
    if (dst >= NN) return;
    unsigned char* arow = aggbuf + (size_t)dst * KBIG;
    // root slot
    unsigned u = *(const unsigned*)(hin + (size_t)dst * HID + lane * 2);
    unsigned pk = __builtin_amdgcn_cvt_pk_fp8_f32(bf2f((unsigned short)(u & 0xFFFF)),
                                                  bf2f((unsigned short)(u >> 16)), 0, false);
    *(unsigned short*)(arow + lane * 2) = (unsigned short)(pk & 0xFFFF);
    int rp[9];
#pragma unroll
    for (int i = 0; i < 9; ++i) rp[i] = rp2[dst * RELS + i];
#pragma unroll
    for (int r = 0; r < RELS; ++r) {
        int beg = rp[r], end = rp[r + 1];
        float a0 = 0.f, a1 = 0.f;
        int e = beg;
        for (; e + 2 <= end; e += 2) {
            int s0 = epk2[e], s1 = epk2[e + 1];
            unsigned u0 = *(const unsigned*)(hin + (size_t)s0 * HID + lane * 2);
            unsigned u1 = *(const unsigned*)(hin + (size_t)s1 * HID + lane * 2);
            a0 += bf2f((unsigned short)(u0 & 0xFFFF)) + bf2f((unsigned short)(u1 & 0xFFFF));
            a1 += bf2f((unsigned short)(u0 >> 16)) + bf2f((unsigned short)(u1 >> 16));
        }
        if (e < end) {
            int s0 = epk2[e];
            unsigned u0 = *(const unsigned*)(hin + (size_t)s0 * HID + lane * 2);
            a0 += bf2f((unsigned short)(u0 & 0xFFFF));
            a1 += bf2f((unsigned short)(u0 >> 16));
        }
        float s = 1.0f / fmaxf((float)(end - beg), 1.0f);
        unsigned w = __builtin_amdgcn_cvt_pk_fp8_f32(a0 * s, a1 * s, 0, false);
        *(unsigned short*)(arow + (1 + r) * HID + lane * 2) = (unsigned short)(w & 0xFFFF);
    }
}

// ---------------- one dense fp8 GEMM per layer: [50000 x 1152] x [1152 x 128],
// relu(+bias) -> bf16 (permuted packed). R3-verified staging/swizzle structure,
// re-derived for 128B fp8 rows (8 chunks of 16B; XOR involution c^(row&7)).
__global__ __launch_bounds__(256) void gemm_big(const unsigned char* __restrict__ aggbuf,
                                                const unsigned char* __restrict__ wt8,
                                                const float* __restrict__ bias,
                                                unsigned short* __restrict__ hout) {
    __shared__ __align__(16) unsigned char As[128 * 128];   // 16 KB fp8, swizzled content
    __shared__ __align__(16) unsigned char Bs[128 * 128];   // 16 KB
    int stripe = blockIdx.x;
    int row0 = stripe * 128;
    int tid = threadIdx.x;
    int wave = tid >> 6, lane = tid & 63;
    int wm = (wave & 1) * 64, wn = (wave >> 1) * 64;
    int quad = lane >> 4, l16 = lane & 15;
    int lr = lane >> 3, lc = lane & 7;   // staging: row-in-group, 16B chunk

    f32x4 acc[4][4];
#pragma unroll
    for (int i = 0; i < 4; ++i)
#pragma unroll
        for (int j = 0; j < 4; ++j) acc[i][j] = (f32x4){0.f, 0.f, 0.f, 0.f};

    for (int p = 0; p < 9; ++p) {
        // stage A panel (128 rows x 128B) + B panel from wt8[n][p*128..]
#pragma unroll
        for (int q = 0; q < 4; ++q) {
            int rb = wave * 32 + q * 8;        // wave-uniform row base (8 rows/call)
            int r = rb + lr;
            int sc = (lc ^ (r & 7)) << 4;      // swizzled source chunk (byte offset)
            int ga = row0 + r; if (ga > NN - 1) ga = NN - 1;   // clamp: tail rows never stored
            gload16(aggbuf + (size_t)ga * KBIG + p * 128 + sc, As + rb * 128);
            gload16(wt8 + (size_t)r * KBIG + p * 128 + sc, Bs + rb * 128);
        }
        __syncthreads();   // panel ready
#pragma unroll
        for (int kc = 0; kc < 4; ++kc) {
            // k-bytes for this instr: kc*32 + quad*8 .. +7
            int ch = kc * 2 + (quad >> 1);
            int half = (quad & 1) * 8;
            long a[4], b[4];
#pragma unroll
            for (int i = 0; i < 4; ++i) {
                int ra = wm + i * 16 + l16;
                int rb2 = wn + i * 16 + l16;
                a[i] = *(const long*)(As + ra * 128 + ((ch ^ (ra & 7)) << 4) + half);
                b[i] = *(const long*)(Bs + rb2 * 128 + ((ch ^ (rb2 & 7)) << 4) + half);
            }
#pragma unroll
            for (int i = 0; i < 4; ++i)
#pragma unroll
                for (int j = 0; j < 4; ++j)
                    acc[i][j] = __builtin_amdgcn_mfma_f32_16x16x32_fp8_fp8(a[i], b[j], acc[i][j], 0, 0, 0);
        }
        __syncthreads();   // all reads done before restage
    }

    // epilogue: relu(acc + bias) -> bf16, perm-packed (R3-verified mapping)
    int pbase = wn + l16 * 4;
    float b0 = bias[wn + l16], b1 = bias[wn + 16 + l16];
    float b2 = bias[wn + 32 + l16], b3 = bias[wn + 48 + l16];
#pragma unroll
    for (int i = 0; i < 4; ++i)
#pragma unroll
        for (int reg = 0; reg < 4; ++reg) {
            int grow = row0 + wm + i * 16 + quad * 4 + reg;
            if (grow >= NN) continue;
            unsigned lo = (unsigned)f2bf(fmaxf(acc[i][0][reg] + b0, 0.f)) |
                          ((unsigned)f2bf(fmaxf(acc[i][1][reg] + b1, 0.f)) << 16);
            unsigned hi = (unsigned)f2bf(fmaxf(acc[i][2][reg] + b2, 0.f)) |
                          ((unsigned)f2bf(fmaxf(acc[i][3][reg] + b3, 0.f)) << 16);
            uint2 pk = {lo, hi};
            *(uint2*)(hout + (size_t)grow * HID + pbase) = pk;
        }
}

// ---------------- global mean pool: sorted-batch register accumulation (position-wise)
__global__ __launch_bounds__(256) void pool_kernel(const unsigned short* __restrict__ habf,
                                                   const int* __restrict__ batch,
                                                   float* __restrict__ psum,
                                                   float* __restrict__ pcnt) {
    int tid = threadIdx.x;
    int f = tid & 127;
    int sub = tid >> 7;
    int base = blockIdx.x * PCHUNK;
    float acc = 0.f, cnt = 0.f;
    int gcur = -1;
    for (int it = 0; it < PCHUNK / 2; ++it) {
        int node = base + it * 2 + sub;
        if (node >= NN) break;
        int g = batch[node];
        if (g != gcur) {
            if (gcur >= 0) {
                atomicAdd(&psum[gcur * HID + f], acc);
                if (f == 0) atomicAdd(&pcnt[gcur], cnt);
            }
            gcur = g; acc = 0.f; cnt = 0.f;
        }
        acc += bf2f(habf[(size_t)node * HID + f]);
        cnt += 1.f;
    }
    if (gcur >= 0) {
        atomicAdd(&psum[gcur * HID + f], acc);
        if (f == 0) atomicAdd(&pcnt[gcur], cnt);
    }
}

// ---------------- head (unpermutes psum)
__global__ void head_kernel(const float* __restrict__ psum, const float* __restrict__ pcnt,
                            const float* __restrict__ g2, const float* __restrict__ b2,
                            const float* __restrict__ m2, const float* __restrict__ v2,
                            const float* __restrict__ fc1w, const float* __restrict__ fc1b,
                            const float* __restrict__ fc2w, const float* __restrict__ fc2b,
                            float* __restrict__ out) {
    __shared__ float v[HID];
    __shared__ float u[HID];
    __shared__ float lg[CLASSES];
    int j = threadIdx.x;
    int pj = permf(j);
    float acc = 0.f;
    for (int g = 0; g < GRAPHS; ++g) {
        float val = psum[g * HID + pj] / fmaxf(pcnt[g], 1.0f);
        val = (val - m2[j]) * rsqrtf(v2[j] + EPSV) * g2[j] + b2[j];
        acc += val;
    }
    v[j] = fmaxf(acc / (float)GRAPHS, 0.f);
    __syncthreads();
    float s = fc1b[j];
    for (int k = 0; k < HID; ++k) s += v[k] * fc1w[k * HID + j];
    u[j] = fmaxf(s, 0.f);
    __syncthreads();
    if (j < CLASSES) {
        float t = fc2b[j];
        for (int k = 0; k < HID; ++k) t += u[k] * fc2w[k * CLASSES + j];
        lg[j] = t;
    }
    __syncthreads();
    if (j < CLASSES) {
        float mx = lg[0];
        for (int c = 1; c < CLASSES; ++c) mx = fmaxf(mx, lg[c]);
        float se = 0.f;
        for (int c = 0; c < CLASSES; ++c) se += expf(lg[c] - mx);
        out[j] = lg[j] - mx - logf(se);
    }
}

extern "C" void kernel_launch(void* const* d_in, const int* in_sizes, int n_in,
                              void* d_out, int out_size, void* d_ws, size_t ws_size,
                              hipStream_t stream) {
    const float* x     = (const float*)d_in[0];
    const int*   ei    = (const int*)d_in[1];
    const int*   ea    = (const int*)d_in[2];
    const int*   batch = (const int*)d_in[3];
    const float* bn1g  = (const float*)d_in[4];
    const float* bn1b  = (const float*)d_in[5];
    const float* bn1m  = (const float*)d_in[6];
    const float* bn1v  = (const float*)d_in[7];
    const float* basis = (const float*)d_in[8];
    const float* comp  = (const float*)d_in[9];
    const float* root  = (const float*)d_in[10];
    const float* bias  = (const float*)d_in[11];
    const float* bn2g  = (const float*)d_in[12];
    const float* bn2b  = (const float*)d_in[13];
    const float* bn2m  = (const float*)d_in[14];
    const float* bn2v  = (const float*)d_in[15];
    const float* fc1w  = (const float*)d_in[16];
    const float* fc1b  = (const float*)d_in[17];
    const float* fc2w  = (const float*)d_in[18];
    const float* fc2b  = (const float*)d_in[19];

    float* ws = (float*)d_ws;
    size_t off = 0;
    unsigned char* wt8 = (unsigned char*)(ws + off); off += (size_t)LAYERS * HID * KBIG / 4;
    unsigned short* hb0 = (unsigned short*)(ws + off); off += (size_t)NN * HID / 2;
    unsigned short* hb1 = (unsigned short*)(ws + off); off += (size_t)NN * HID / 2;
    unsigned char* aggbuf = (unsigned char*)(ws + off); off += (size_t)NN * KBIG / 4;   // 57.6 MB
    float* psum   = ws + off; off += (size_t)GRAPHS * HID + GRAPHS;
    float* pcnt   = psum + GRAPHS * HID;
    int* cnt      = (int*)(ws + off); off += (size_t)NSEG;
    int* rowptr2  = (int*)(ws + off); off += (size_t)NSEG + 1;
    int* fillcnt2 = (int*)(ws + off); off += (size_t)NSEG;
    int* bsum     = (int*)(ws + off); off += (size_t)SCAN_NBLK2;
    int* epk2     = (int*)(ws + off); off += (size_t)NE;
    if (ws_size < off * sizeof(float)) return;

    hipMemsetAsync(psum, 0, (GRAPHS * HID + GRAPHS) * sizeof(float), stream);
    hipMemsetAsync(cnt, 0, (size_t)NSEG * sizeof(int), stream);
    hipMemsetAsync(fillcnt2, 0, (size_t)NSEG * sizeof(int), stream);

    build_wcat<<<LAYERS * 64, 256, 0, stream>>>(basis, comp, root, wt8);
    bn1_kernel<<<(NN * HID + 255) / 256, 256, 0, stream>>>(x, bn1g, bn1b, bn1m, bn1v, hb0);

    deg_kernel<<<(NE + 255) / 256, 256, 0, stream>>>(ei, ea, cnt);
    scan_partial<<<SCAN_NBLK2, 256, 0, stream>>>(cnt, rowptr2, bsum);
    scan_bsum<<<1, 512, 0, stream>>>(bsum);
    scan_add<<<(NSEG + 255) / 256, 256, 0, stream>>>(rowptr2, bsum);
    fill_kernel<<<(NE + 255) / 256, 256, 0, stream>>>(ei, ea, rowptr2, fillcnt2, epk2);

    const unsigned short* hin = hb0;
    unsigned short* hout = hb1;
    for (int l = 0; l < LAYERS; ++l) {
        agg_kernel<<<(NN + 3) / 4, 256, 0, stream>>>(hin, rowptr2, epk2, aggbuf);
        gemm_big<<<NSTRIPE, 256, 0, stream>>>(aggbuf, wt8 + (size_t)l * HID * KBIG,
                                              bias + (size_t)l * HID, hout);
        const unsigned short* t = hin; hin = hout; hout = (unsigned short*)t;
    }

    pool_kernel<<<(NN + PCHUNK - 1) / PCHUNK, 256, 0, stream>>>(hin, batch, psum, pcnt);
    head_kernel<<<1, 128, 0, stream>>>(psum, pcnt, bn2g, bn2b, bn2m, bn2v,
                                       fc1w, fc1b, fc2w, fc2b, (float*)d_out);
}